// Round 3
// baseline (601.048 us; speedup 1.0000x reference)
//
#include <hip/hip_runtime.h>

// GAT layer, N=8192, H=4, d=128.
// softmax_j(src_i + tgt_j) masked == adj-normalized w_j = exp(tgt_j); src cancels:
//   out[i,d] = 0.25 * sum_h ( (adj @ (w_h*ht_h))[i,d] / (adj @ w_h)[i] )
// Pipeline:
//   k0: Wt = W^T
//   k1: HT = leakyrelu(h @ W) bf16 MFMA        [8192 x 512]
//   k2: build Yt bf16 [528][8192]: rows 0..511 = w[g,j]*ht[j,g,d];
//       512..515 = w[g,j]; 516..527 = 0.
//   k2b: conv_adj: adj int32 -> Ab bf16 [8192][8192]   (128 MB, L3-resident)
//   k3: C += Ab @ Y, pure global_load_lds staging both sides (m97 shape),
//       K-split 4 via fp32 atomics, grid (4,64,4); denominator fused in cb==0.
//   k4: out = 0.25 * sum_g C[:,g*128+d]/S[g,:]
// ws: big path needs ~169 MB; falls back to round-2 int32-convert GEMM if less.

typedef unsigned short u16;
typedef unsigned int u32;
using bf16x8 = __attribute__((ext_vector_type(8))) short;
using f32x4  = __attribute__((ext_vector_type(4))) float;

typedef const void __attribute__((address_space(1))) gas_void;
typedef void __attribute__((address_space(3))) las_void;
#define GLD16(g, l) __builtin_amdgcn_global_load_lds((gas_void*)(g), (las_void*)(l), 16, 0, 0)

__device__ __forceinline__ u16 f2bf(float f) {
  u32 u = __float_as_uint(f);
  return (u16)((u + 0x7FFFu + ((u >> 16) & 1u)) >> 16);  // RNE
}
__device__ __forceinline__ float bf2f(u16 u) {
  return __uint_as_float(((u32)u) << 16);
}

// ---------------- k0: transpose W [256][512] -> Wt [512][256] ----------------
__global__ void transpose_w(const float* __restrict__ W, float* __restrict__ Wt) {
  __shared__ float tile[32][33];
  int cb = blockIdx.x * 32, kb = blockIdx.y * 32;
  int tc = threadIdx.x & 31, tr = threadIdx.x >> 5;
  for (int p = 0; p < 32; p += 8)
    tile[tr + p][tc] = W[(size_t)(kb + tr + p) * 512 + cb + tc];
  __syncthreads();
  for (int p = 0; p < 32; p += 8)
    Wt[(size_t)(cb + tr + p) * 256 + kb + tc] = tile[tc][tr + p];
}

// ---------------- k1: HT = leaky(h @ W), bf16 out [8192][512] ----------------
__global__ void ht_gemm(const float* __restrict__ h, const float* __restrict__ Wt,
                        u16* __restrict__ HT) {
  __shared__ __align__(16) u16 Abuf[128 * 40];
  __shared__ __align__(16) u16 Bbuf[128 * 40];
  int tid = threadIdx.x;
  int cb = blockIdx.x, rb = blockIdx.y;
  int r0 = rb * 128, c0 = cb * 128;
  int lane = tid & 63, wv = tid >> 6;
  int wr = wv >> 1, wc = wv & 1;
  int mrow = lane & 15, q = lane >> 4;
  int ch = tid & 7, m0 = tid >> 3;

  f32x4 acc[4][4];
#pragma unroll
  for (int i = 0; i < 4; i++)
#pragma unroll
    for (int j = 0; j < 4; j++) acc[i][j] = f32x4{0.f, 0.f, 0.f, 0.f};

  for (int kt = 0; kt < 256; kt += 32) {
    __syncthreads();
#pragma unroll
    for (int mp = 0; mp < 128; mp += 32) {
      int m = m0 + mp;
      float4 v = *(const float4*)(&h[(size_t)(r0 + m) * 256 + kt + ch * 4]);
      uint2 p;
      p.x = (u32)f2bf(v.x) | ((u32)f2bf(v.y) << 16);
      p.y = (u32)f2bf(v.z) | ((u32)f2bf(v.w) << 16);
      *(uint2*)(&Abuf[m * 40 + ch * 4]) = p;
      float4 u = *(const float4*)(&Wt[(size_t)(c0 + m) * 256 + kt + ch * 4]);
      uint2 r;
      r.x = (u32)f2bf(u.x) | ((u32)f2bf(u.y) << 16);
      r.y = (u32)f2bf(u.z) | ((u32)f2bf(u.w) << 16);
      *(uint2*)(&Bbuf[m * 40 + ch * 4]) = r;
    }
    __syncthreads();
    bf16x8 af[4], bfv[4];
#pragma unroll
    for (int i = 0; i < 4; i++)
      af[i] = *(const bf16x8*)(&Abuf[(wr * 64 + i * 16 + mrow) * 40 + q * 8]);
#pragma unroll
    for (int j = 0; j < 4; j++)
      bfv[j] = *(const bf16x8*)(&Bbuf[(wc * 64 + j * 16 + mrow) * 40 + q * 8]);
#pragma unroll
    for (int i = 0; i < 4; i++)
#pragma unroll
      for (int j = 0; j < 4; j++)
        acc[i][j] = __builtin_amdgcn_mfma_f32_16x16x32_bf16(af[i], bfv[j], acc[i][j], 0, 0, 0);
  }
#pragma unroll
  for (int i = 0; i < 4; i++)
#pragma unroll
    for (int j = 0; j < 4; j++)
#pragma unroll
      for (int r = 0; r < 4; r++) {
        int gi = r0 + wr * 64 + i * 16 + q * 4 + r;
        int gc = c0 + wc * 64 + j * 16 + mrow;
        float v = acc[i][j][r];
        v = v >= 0.f ? v : 0.1f * v;
        HT[(size_t)gi * 512 + gc] = f2bf(v);
      }
}

// ---------------- k2: build Yt [528][8192] bf16, coalesced stores ----------------
__global__ void build_yt(const u16* __restrict__ HT, const float* __restrict__ a,
                         u16* __restrict__ Yt) {
  __shared__ u16 sht[64][528];
  __shared__ float swv[64 * 4];
  __shared__ float sa[512];
  int t = threadIdx.x;
  int j0 = blockIdx.x * 64;
  for (int i = t; i < 512; i += 256) {
    int g = i >> 7, d = i & 127;
    sa[i] = a[g * 256 + 128 + d];
  }
#pragma unroll
  for (int p = 0; p < 16; ++p) {
    int el = t + 256 * p;
    int row = el >> 6, col8 = el & 63;
    *(uint4*)(&sht[row][col8 * 8]) = *(const uint4*)(&HT[(size_t)(j0 + row) * 512 + col8 * 8]);
  }
  __syncthreads();
  {
    int jl = t >> 2, g = t & 3;
    float acc = 0.f;
    for (int d = 0; d < 128; ++d)
      acc += bf2f(sht[jl][g * 128 + d]) * sa[g * 128 + d];
    swv[jl * 4 + g] = __expf(acc);
  }
  __syncthreads();
  int oj = (t & 7) * 8, oc = t >> 3;
  for (int pass = 0; pass < 17; ++pass) {
    int c = pass * 32 + oc;
    if (c >= 528) break;
    u32 pk[4] = {0u, 0u, 0u, 0u};
    if (c < 512) {
      int g = c >> 7;
#pragma unroll
      for (int u = 0; u < 4; ++u) {
        int j = oj + 2 * u;
        float v0 = bf2f(sht[j][c]) * swv[j * 4 + g];
        float v1 = bf2f(sht[j + 1][c]) * swv[(j + 1) * 4 + g];
        pk[u] = (u32)f2bf(v0) | ((u32)f2bf(v1) << 16);
      }
    } else if (c < 516) {
      int g = c - 512;
#pragma unroll
      for (int u = 0; u < 4; ++u) {
        int j = oj + 2 * u;
        float v0 = swv[j * 4 + g];
        float v1 = swv[(j + 1) * 4 + g];
        pk[u] = (u32)f2bf(v0) | ((u32)f2bf(v1) << 16);
      }
    }
    *(uint4*)(&Yt[(size_t)c * 8192 + j0 + oj]) = make_uint4(pk[0], pk[1], pk[2], pk[3]);
  }
}

// ---------------- k2b: adj int32 -> bf16 [8192][8192] ----------------
// 16 elems/thread: 4x int4 loads -> 2x uint4 store (32 B)
__global__ void conv_adj(const int* __restrict__ adj, u16* __restrict__ Ab) {
  size_t base = ((size_t)blockIdx.x * 256 + threadIdx.x) * 16;
  u32 pk[8];
#pragma unroll
  for (int c = 0; c < 4; ++c) {
    int4 v = *(const int4*)(&adj[base + c * 4]);
    pk[c * 2]     = 16256u * ((u32)v.x | ((u32)v.y << 16));
    pk[c * 2 + 1] = 16256u * ((u32)v.z | ((u32)v.w << 16));
  }
  *(uint4*)(&Ab[base])     = make_uint4(pk[0], pk[1], pk[2], pk[3]);
  *(uint4*)(&Ab[base + 8]) = make_uint4(pk[4], pk[5], pk[6], pk[7]);
}

// ---------------- k3 (big-ws path): C += Ab @ Y, pure GLD16 staging ----------------
// grid (4, 64, 4): cb head col block, rb row band, kh K quarter.
// cb==0 blocks also accumulate denominators S via wc==0 waves.
__global__ __launch_bounds__(256) void adj_gemm_bf(const u16* __restrict__ Ab,
                                                   const u16* __restrict__ Yt,
                                                   float* __restrict__ C,
                                                   float* __restrict__ S) {
  __shared__ __align__(16) u16 Abuf[128 * 32];
  __shared__ __align__(16) u16 Bbuf[128 * 32];
  __shared__ __align__(16) u16 Bden[16 * 32];
  int tid = threadIdx.x;
  int cb = blockIdx.x, rb = blockIdx.y, kh = blockIdx.z;
  int r0 = rb * 128, c0 = cb * 128, k0 = kh * 2048;
  int lane = tid & 63, wv = tid >> 6;
  int wr = wv >> 1, wc = wv & 1;
  int mrow = lane & 15, q = lane >> 4;
  int brow = lane >> 2, bq = lane & 3;
  bool do_den = (cb == 0) && (wc == 0);

  f32x4 acc[4][4];
#pragma unroll
  for (int i = 0; i < 4; i++)
#pragma unroll
    for (int j = 0; j < 4; j++) acc[i][j] = f32x4{0.f, 0.f, 0.f, 0.f};
  f32x4 accD[4];
#pragma unroll
  for (int i = 0; i < 4; i++) accD[i] = f32x4{0.f, 0.f, 0.f, 0.f};

  for (int kt = k0; kt < k0 + 2048; kt += 32) {
    __syncthreads();
    // A: 2 calls/wave, 16 rows each
    GLD16(&Ab[(size_t)(r0 + wv * 16 + brow) * 8192 + kt + bq * 8],
          &Abuf[(wv * 16) * 32]);
    GLD16(&Ab[(size_t)(r0 + 64 + wv * 16 + brow) * 8192 + kt + bq * 8],
          &Abuf[(64 + wv * 16) * 32]);
    // B: 2 calls/wave
    GLD16(&Yt[(size_t)(c0 + wv * 16 + brow) * 8192 + kt + bq * 8],
          &Bbuf[(wv * 16) * 32]);
    GLD16(&Yt[(size_t)(c0 + 64 + wv * 16 + brow) * 8192 + kt + bq * 8],
          &Bbuf[(64 + wv * 16) * 32]);
    if (cb == 0 && wv == 0)
      GLD16(&Yt[(size_t)(512 + brow) * 8192 + kt + bq * 8], Bden);
    __syncthreads();
    bf16x8 af[4], bfv[4];
#pragma unroll
    for (int i = 0; i < 4; i++)
      af[i] = *(const bf16x8*)(&Abuf[(wr * 64 + i * 16 + mrow) * 32 + q * 8]);
#pragma unroll
    for (int j = 0; j < 4; j++)
      bfv[j] = *(const bf16x8*)(&Bbuf[(wc * 64 + j * 16 + mrow) * 32 + q * 8]);
#pragma unroll
    for (int i = 0; i < 4; i++)
#pragma unroll
      for (int j = 0; j < 4; j++)
        acc[i][j] = __builtin_amdgcn_mfma_f32_16x16x32_bf16(af[i], bfv[j], acc[i][j], 0, 0, 0);
    if (do_den) {
      bf16x8 bd = *(const bf16x8*)(&Bden[mrow * 32 + q * 8]);
#pragma unroll
      for (int i = 0; i < 4; i++)
        accD[i] = __builtin_amdgcn_mfma_f32_16x16x32_bf16(af[i], bd, accD[i], 0, 0, 0);
    }
  }
#pragma unroll
  for (int i = 0; i < 4; i++)
#pragma unroll
    for (int j = 0; j < 4; j++)
#pragma unroll
      for (int r = 0; r < 4; r++) {
        int gi = r0 + wr * 64 + i * 16 + q * 4 + r;
        int gc = c0 + wc * 64 + j * 16 + mrow;
        atomicAdd(&C[(size_t)gi * 512 + gc], acc[i][j][r]);
      }
  if (do_den && mrow < 4) {
#pragma unroll
    for (int i = 0; i < 4; i++)
#pragma unroll
      for (int r = 0; r < 4; r++) {
        int gi = r0 + wr * 64 + i * 16 + q * 4 + r;
        atomicAdd(&S[(size_t)mrow * 8192 + gi], accD[i][r]);
      }
  }
}

// ---------------- k3 (fallback, round-2 path): in-loop int32 convert ----------------
__global__ __launch_bounds__(256) void adj_gemm_i32(const int* __restrict__ adj,
                                                    const u16* __restrict__ Yt,
                                                    float* __restrict__ C,
                                                    float* __restrict__ S) {
  __shared__ __align__(16) u16 Abuf[128 * 40];
  __shared__ __align__(16) u16 Bbuf[128 * 32];
  __shared__ __align__(16) u16 Bden[16 * 32];
  int tid = threadIdx.x;
  int cb = blockIdx.x, rb = blockIdx.y, kh = blockIdx.z;
  int r0 = rb * 128, c0 = cb * 128, k0 = kh * 2048;
  int lane = tid & 63, wv = tid >> 6;
  int wr = wv >> 1, wc = wv & 1;
  int mrow = lane & 15, q = lane >> 4;
  int ch = tid & 7, m0 = tid >> 3;
  int brow = lane >> 2, bq = lane & 3;
  bool do_den = (cb == 0) && (wc == 0);

  f32x4 acc[4][4];
#pragma unroll
  for (int i = 0; i < 4; i++)
#pragma unroll
    for (int j = 0; j < 4; j++) acc[i][j] = f32x4{0.f, 0.f, 0.f, 0.f};
  f32x4 accD[4];
#pragma unroll
  for (int i = 0; i < 4; i++) accD[i] = f32x4{0.f, 0.f, 0.f, 0.f};

  for (int kt = k0; kt < k0 + 2048; kt += 32) {
    __syncthreads();
#pragma unroll
    for (int mp = 0; mp < 128; mp += 32) {
      int m = m0 + mp;
      int4 v = *(const int4*)(&adj[(size_t)(r0 + m) * 8192 + kt + ch * 4]);
      uint2 p;
      p.x = 16256u * ((u32)v.x | ((u32)v.y << 16));
      p.y = 16256u * ((u32)v.z | ((u32)v.w << 16));
      *(uint2*)(&Abuf[m * 40 + ch * 4]) = p;
    }
    GLD16(&Yt[(size_t)(c0 + wv * 16 + brow) * 8192 + kt + bq * 8],
          &Bbuf[(wv * 16) * 32]);
    GLD16(&Yt[(size_t)(c0 + 64 + wv * 16 + brow) * 8192 + kt + bq * 8],
          &Bbuf[(64 + wv * 16) * 32]);
    if (cb == 0 && wv == 0)
      GLD16(&Yt[(size_t)(512 + brow) * 8192 + kt + bq * 8], Bden);
    __syncthreads();
    bf16x8 af[4], bfv[4];
#pragma unroll
    for (int i = 0; i < 4; i++)
      af[i] = *(const bf16x8*)(&Abuf[(wr * 64 + i * 16 + mrow) * 40 + q * 8]);
#pragma unroll
    for (int j = 0; j < 4; j++)
      bfv[j] = *(const bf16x8*)(&Bbuf[(wc * 64 + j * 16 + mrow) * 32 + q * 8]);
#pragma unroll
    for (int i = 0; i < 4; i++)
#pragma unroll
      for (int j = 0; j < 4; j++)
        acc[i][j] = __builtin_amdgcn_mfma_f32_16x16x32_bf16(af[i], bfv[j], acc[i][j], 0, 0, 0);
    if (do_den) {
      bf16x8 bd = *(const bf16x8*)(&Bden[mrow * 32 + q * 8]);
#pragma unroll
      for (int i = 0; i < 4; i++)
        accD[i] = __builtin_amdgcn_mfma_f32_16x16x32_bf16(af[i], bd, accD[i], 0, 0, 0);
    }
  }
#pragma unroll
  for (int i = 0; i < 4; i++)
#pragma unroll
    for (int j = 0; j < 4; j++)
#pragma unroll
      for (int r = 0; r < 4; r++) {
        int gi = r0 + wr * 64 + i * 16 + q * 4 + r;
        int gc = c0 + wc * 64 + j * 16 + mrow;
        atomicAdd(&C[(size_t)gi * 512 + gc], acc[i][j][r]);
      }
  if (do_den && mrow < 4) {
#pragma unroll
    for (int i = 0; i < 4; i++)
#pragma unroll
      for (int r = 0; r < 4; r++) {
        int gi = r0 + wr * 64 + i * 16 + q * 4 + r;
        atomicAdd(&S[(size_t)mrow * 8192 + gi], accD[i][r]);
      }
  }
}

// ---------------- k4: out = 0.25 * sum_g C[:,g*128+d]/S[g,:] ----------------
__global__ void finalize_gat(const float* __restrict__ C, const float* __restrict__ S,
                             float* __restrict__ out) {
  int idx = blockIdx.x * 256 + threadIdx.x;
  int i = idx >> 7, d = idx & 127;
  float s = 0.f;
#pragma unroll
  for (int g = 0; g < 4; ++g)
    s += C[(size_t)i * 512 + g * 128 + d] / S[(size_t)g * 8192 + i];
  out[idx] = 0.25f * s;
}

extern "C" void kernel_launch(void* const* d_in, const int* in_sizes, int n_in,
                              void* d_out, int out_size, void* d_ws, size_t ws_size,
                              hipStream_t stream) {
  const float* h   = (const float*)d_in[0];
  const int*   adj = (const int*)d_in[1];
  const float* W   = (const float*)d_in[2];
  const float* a   = (const float*)d_in[3];
  float* out = (float*)d_out;
  char* ws = (char*)d_ws;
  // ws: Wt 512K | HT 8M | Yt 8.65M | C 16M | S 128K | Ab 128M (big path)
  float* Wt = (float*)(ws + 0);
  u16*   HT = (u16*)(ws + 524288);
  u16*   Yt = (u16*)(ws + 8912896);
  float* C  = (float*)(ws + 17563648);
  float* S  = (float*)(ws + 34340864);
  u16*   Ab = (u16*)(ws + 34471936);
  const size_t NEED_BIG = 34471936ull + 134217728ull;

  hipMemsetAsync(C, 0, (size_t)8192 * 512 * 4, stream);
  hipMemsetAsync(S, 0, (size_t)4 * 8192 * 4, stream);
  transpose_w<<<dim3(16, 8), 256, 0, stream>>>(W, Wt);
  ht_gemm<<<dim3(4, 64), 256, 0, stream>>>(h, Wt, HT);
  build_yt<<<dim3(128), 256, 0, stream>>>(HT, a, Yt);
  if (ws_size >= NEED_BIG) {
    conv_adj<<<dim3(16384), 256, 0, stream>>>(adj, Ab);
    adj_gemm_bf<<<dim3(4, 64, 4), 256, 0, stream>>>(Ab, Yt, C, S);
  } else {
    adj_gemm_i32<<<dim3(4, 64, 4), 256, 0, stream>>>(adj, Yt, C, S);
  }
  finalize_gat<<<dim3(4096), 256, 0, stream>>>(C, S, out);
}

// Round 4
// 504.295 us; speedup vs baseline: 1.1919x; 1.1919x over previous
//
#include <hip/hip_runtime.h>

// GAT layer, N=8192, H=4, d=128.
// softmax_j(src_i + tgt_j) masked == adj-normalized w_j = exp(tgt_j); src cancels:
//   out[i,d] = 0.25 * sum_h ( (adj @ (w_h*ht_h))[i,d] / (adj @ w_h)[i] )
// Pipeline:
//   k0: Wt = W^T
//   k1: HT = leakyrelu(h @ W) bf16 MFMA        [8192 x 512]
//   k2: build Yt bf16 [528][8192]: rows 0..511 = w[g,j]*ht[j,g,d];
//       512..515 = w[g,j]; 516..527 = 0.
//   k3: adj_gemm fused: one block = 128 rows x ALL 512 cols + denominator.
//       adj read ONCE (int32->bf16 in-loop), B via global_load_lds w=16.
//       K-split 4 -> per-kh C/S buffers (no atomics, no memset).
//   k4: out = 0.25 * sum_g (sum_kh C_kh)[i,512g+d] / (sum_kh S_kh)[g,i]
// ws ~85 MB: Wt 0.5M | HT 8M | Yt 8.65M | C 64M | S 0.5M

typedef unsigned short u16;
typedef unsigned int u32;
using bf16x8 = __attribute__((ext_vector_type(8))) short;
using f32x4  = __attribute__((ext_vector_type(4))) float;

typedef const void __attribute__((address_space(1))) gas_void;
typedef void __attribute__((address_space(3))) las_void;
#define GLD16(g, l) __builtin_amdgcn_global_load_lds((gas_void*)(g), (las_void*)(l), 16, 0, 0)

__device__ __forceinline__ u16 f2bf(float f) {
  u32 u = __float_as_uint(f);
  return (u16)((u + 0x7FFFu + ((u >> 16) & 1u)) >> 16);  // RNE
}
__device__ __forceinline__ float bf2f(u16 u) {
  return __uint_as_float(((u32)u) << 16);
}

// ---------------- k0: transpose W [256][512] -> Wt [512][256] ----------------
__global__ void transpose_w(const float* __restrict__ W, float* __restrict__ Wt) {
  __shared__ float tile[32][33];
  int cb = blockIdx.x * 32, kb = blockIdx.y * 32;
  int tc = threadIdx.x & 31, tr = threadIdx.x >> 5;
  for (int p = 0; p < 32; p += 8)
    tile[tr + p][tc] = W[(size_t)(kb + tr + p) * 512 + cb + tc];
  __syncthreads();
  for (int p = 0; p < 32; p += 8)
    Wt[(size_t)(cb + tr + p) * 256 + kb + tc] = tile[tc][tr + p];
}

// ---------------- k1: HT = leaky(h @ W), bf16 out [8192][512] ----------------
__global__ void ht_gemm(const float* __restrict__ h, const float* __restrict__ Wt,
                        u16* __restrict__ HT) {
  __shared__ __align__(16) u16 Abuf[128 * 40];
  __shared__ __align__(16) u16 Bbuf[128 * 40];
  int tid = threadIdx.x;
  int cb = blockIdx.x, rb = blockIdx.y;
  int r0 = rb * 128, c0 = cb * 128;
  int lane = tid & 63, wv = tid >> 6;
  int wr = wv >> 1, wc = wv & 1;
  int mrow = lane & 15, q = lane >> 4;
  int ch = tid & 7, m0 = tid >> 3;

  f32x4 acc[4][4];
#pragma unroll
  for (int i = 0; i < 4; i++)
#pragma unroll
    for (int j = 0; j < 4; j++) acc[i][j] = f32x4{0.f, 0.f, 0.f, 0.f};

  for (int kt = 0; kt < 256; kt += 32) {
    __syncthreads();
#pragma unroll
    for (int mp = 0; mp < 128; mp += 32) {
      int m = m0 + mp;
      float4 v = *(const float4*)(&h[(size_t)(r0 + m) * 256 + kt + ch * 4]);
      uint2 p;
      p.x = (u32)f2bf(v.x) | ((u32)f2bf(v.y) << 16);
      p.y = (u32)f2bf(v.z) | ((u32)f2bf(v.w) << 16);
      *(uint2*)(&Abuf[m * 40 + ch * 4]) = p;
      float4 u = *(const float4*)(&Wt[(size_t)(c0 + m) * 256 + kt + ch * 4]);
      uint2 r;
      r.x = (u32)f2bf(u.x) | ((u32)f2bf(u.y) << 16);
      r.y = (u32)f2bf(u.z) | ((u32)f2bf(u.w) << 16);
      *(uint2*)(&Bbuf[m * 40 + ch * 4]) = r;
    }
    __syncthreads();
    bf16x8 af[4], bfv[4];
#pragma unroll
    for (int i = 0; i < 4; i++)
      af[i] = *(const bf16x8*)(&Abuf[(wr * 64 + i * 16 + mrow) * 40 + q * 8]);
#pragma unroll
    for (int j = 0; j < 4; j++)
      bfv[j] = *(const bf16x8*)(&Bbuf[(wc * 64 + j * 16 + mrow) * 40 + q * 8]);
#pragma unroll
    for (int i = 0; i < 4; i++)
#pragma unroll
      for (int j = 0; j < 4; j++)
        acc[i][j] = __builtin_amdgcn_mfma_f32_16x16x32_bf16(af[i], bfv[j], acc[i][j], 0, 0, 0);
  }
#pragma unroll
  for (int i = 0; i < 4; i++)
#pragma unroll
    for (int j = 0; j < 4; j++)
#pragma unroll
      for (int r = 0; r < 4; r++) {
        int gi = r0 + wr * 64 + i * 16 + q * 4 + r;
        int gc = c0 + wc * 64 + j * 16 + mrow;
        float v = acc[i][j][r];
        v = v >= 0.f ? v : 0.1f * v;
        HT[(size_t)gi * 512 + gc] = f2bf(v);
      }
}

// ---------------- k2: build Yt [528][8192] bf16 ----------------
__global__ void build_yt(const u16* __restrict__ HT, const float* __restrict__ a,
                         u16* __restrict__ Yt) {
  __shared__ u16 sht[64][528];
  __shared__ float swv[64 * 4];
  __shared__ float sa[512];
  int t = threadIdx.x;
  int j0 = blockIdx.x * 64;
  for (int i = t; i < 512; i += 256) {
    int g = i >> 7, d = i & 127;
    sa[i] = a[g * 256 + 128 + d];
  }
#pragma unroll
  for (int p = 0; p < 16; ++p) {
    int el = t + 256 * p;
    int row = el >> 6, col8 = el & 63;
    *(uint4*)(&sht[row][col8 * 8]) = *(const uint4*)(&HT[(size_t)(j0 + row) * 512 + col8 * 8]);
  }
  __syncthreads();
  {
    int jl = t >> 2, g = t & 3;
    float acc = 0.f;
#pragma unroll
    for (int d8 = 0; d8 < 16; ++d8) {
      bf16x8 v = *(const bf16x8*)(&sht[jl][g * 128 + d8 * 8]);
#pragma unroll
      for (int u = 0; u < 8; ++u)
        acc += bf2f((u16)v[u]) * sa[g * 128 + d8 * 8 + u];
    }
    swv[jl * 4 + g] = __expf(acc);
  }
  __syncthreads();
  int oj = (t & 7) * 8, oc = t >> 3;
  for (int pass = 0; pass < 17; ++pass) {
    int c = pass * 32 + oc;
    if (c >= 528) break;
    u32 pk[4] = {0u, 0u, 0u, 0u};
    if (c < 512) {
      int g = c >> 7;
#pragma unroll
      for (int u = 0; u < 4; ++u) {
        int j = oj + 2 * u;
        float v0 = bf2f(sht[j][c]) * swv[j * 4 + g];
        float v1 = bf2f(sht[j + 1][c]) * swv[(j + 1) * 4 + g];
        pk[u] = (u32)f2bf(v0) | ((u32)f2bf(v1) << 16);
      }
    } else if (c < 516) {
      int g = c - 512;
#pragma unroll
      for (int u = 0; u < 4; ++u) {
        int j = oj + 2 * u;
        float v0 = swv[j * 4 + g];
        float v1 = swv[(j + 1) * 4 + g];
        pk[u] = (u32)f2bf(v0) | ((u32)f2bf(v1) << 16);
      }
    }
    *(uint4*)(&Yt[(size_t)c * 8192 + j0 + oj]) = make_uint4(pk[0], pk[1], pk[2], pk[3]);
  }
}

// ---------------- k3: fused adj GEMM ----------------
// grid (64, 4) = (rb, kh), 512 threads = 8 waves (2 wr x 4 wc), wave tile 64x128.
// C_kh [8192][512], S_kh [4][8192] written directly (no atomics).
__global__ __launch_bounds__(512) void adj_gemm(const int* __restrict__ adj,
                                                const u16* __restrict__ Yt,
                                                float* __restrict__ C,
                                                float* __restrict__ S) {
  __shared__ __align__(16) u16 Abuf[128 * 32];   // 8 KB
  __shared__ __align__(16) u16 Bbuf[512 * 32];   // 32 KB
  __shared__ __align__(16) u16 Bden[16 * 32];    // 1 KB
  int tid = threadIdx.x;
  int rb = blockIdx.x, kh = blockIdx.y;
  int r0 = rb * 128, k0 = kh * 2048;
  int lane = tid & 63, wv = tid >> 6;
  int wr = wv >> 2, wc = wv & 3;
  int mrow = lane & 15, q = lane >> 4;
  int am = tid >> 2, ak = (tid & 3) * 8;   // A staging: row, k-octet
  int brow = lane >> 2, bq = lane & 3;     // B staging lane split
  bool do_den = (wc == 0);

  f32x4 acc[4][8];
#pragma unroll
  for (int i = 0; i < 4; i++)
#pragma unroll
    for (int j = 0; j < 8; j++) acc[i][j] = f32x4{0.f, 0.f, 0.f, 0.f};
  f32x4 accD[4];
#pragma unroll
  for (int i = 0; i < 4; i++) accD[i] = f32x4{0.f, 0.f, 0.f, 0.f};

  for (int kt = k0; kt < k0 + 2048; kt += 32) {
    __syncthreads();
    {  // A: 128 rows x 32 k, int32 -> bf16, one uint4 LDS write per thread
      const int* ap = &adj[(size_t)(r0 + am) * 8192 + kt + ak];
      int4 v0 = *(const int4*)(ap);
      int4 v1 = *(const int4*)(ap + 4);
      uint4 p;  // {0,1} -> bf16 bits 0x3F80*x, packed pairwise
      p.x = 16256u * ((u32)v0.x | ((u32)v0.y << 16));
      p.y = 16256u * ((u32)v0.z | ((u32)v0.w << 16));
      p.z = 16256u * ((u32)v1.x | ((u32)v1.y << 16));
      p.w = 16256u * ((u32)v1.z | ((u32)v1.w << 16));
      *(uint4*)(&Abuf[am * 32 + ak]) = p;
    }
    // B: 512 rows x 32 k via async global->LDS (16 rows per wave-call)
#pragma unroll
    for (int p = 0; p < 4; ++p)
      GLD16(&Yt[(size_t)(p * 128 + wv * 16 + brow) * 8192 + kt + bq * 8],
            &Bbuf[(p * 128 + wv * 16) * 32]);
    if (wv == 0)
      GLD16(&Yt[(size_t)(512 + brow) * 8192 + kt + bq * 8], Bden);
    __syncthreads();
    bf16x8 af[4], bfv[8];
#pragma unroll
    for (int i = 0; i < 4; i++)
      af[i] = *(const bf16x8*)(&Abuf[(wr * 64 + i * 16 + mrow) * 32 + q * 8]);
#pragma unroll
    for (int j = 0; j < 8; j++)
      bfv[j] = *(const bf16x8*)(&Bbuf[(wc * 128 + j * 16 + mrow) * 32 + q * 8]);
#pragma unroll
    for (int i = 0; i < 4; i++)
#pragma unroll
      for (int j = 0; j < 8; j++)
        acc[i][j] = __builtin_amdgcn_mfma_f32_16x16x32_bf16(af[i], bfv[j], acc[i][j], 0, 0, 0);
    if (do_den) {
      bf16x8 bd = *(const bf16x8*)(&Bden[mrow * 32 + q * 8]);
#pragma unroll
      for (int i = 0; i < 4; i++)
        accD[i] = __builtin_amdgcn_mfma_f32_16x16x32_bf16(af[i], bd, accD[i], 0, 0, 0);
    }
  }
  float* Ck = C + (size_t)kh * 8192 * 512;
#pragma unroll
  for (int i = 0; i < 4; i++)
#pragma unroll
    for (int j = 0; j < 8; j++)
#pragma unroll
      for (int r = 0; r < 4; r++) {
        int gi = r0 + wr * 64 + i * 16 + q * 4 + r;
        int gc = wc * 128 + j * 16 + mrow;
        Ck[(size_t)gi * 512 + gc] = acc[i][j][r];
      }
  if (do_den && mrow < 4) {
    float* Sk = S + (size_t)kh * 4 * 8192;
#pragma unroll
    for (int i = 0; i < 4; i++)
#pragma unroll
      for (int r = 0; r < 4; r++) {
        int gi = r0 + wr * 64 + i * 16 + q * 4 + r;
        Sk[(size_t)mrow * 8192 + gi] = accD[i][r];
      }
  }
}

// ---------------- k4: combine K-split + heads ----------------
__global__ void finalize_gat(const float* __restrict__ C, const float* __restrict__ S,
                             float* __restrict__ out) {
  int idx = blockIdx.x * 256 + threadIdx.x;
  int i = idx >> 7, d = idx & 127;
  float s = 0.f;
#pragma unroll
  for (int g = 0; g < 4; ++g) {
    float num = 0.f, den = 0.f;
#pragma unroll
    for (int kh = 0; kh < 4; ++kh) {
      num += C[(size_t)kh * 8192 * 512 + (size_t)i * 512 + g * 128 + d];
      den += S[(size_t)kh * 4 * 8192 + (size_t)g * 8192 + i];
    }
    s += num / den;
  }
  out[idx] = 0.25f * s;
}

extern "C" void kernel_launch(void* const* d_in, const int* in_sizes, int n_in,
                              void* d_out, int out_size, void* d_ws, size_t ws_size,
                              hipStream_t stream) {
  const float* h   = (const float*)d_in[0];
  const int*   adj = (const int*)d_in[1];
  const float* W   = (const float*)d_in[2];
  const float* a   = (const float*)d_in[3];
  float* out = (float*)d_out;
  char* ws = (char*)d_ws;
  // ws: Wt 0.5M | HT 8M | Yt 8.65M | C 64M (4 x 16M) | S 0.5M  (~85 MB)
  float* Wt = (float*)(ws + 0);
  u16*   HT = (u16*)(ws + 524288);
  u16*   Yt = (u16*)(ws + 8912896);
  float* C  = (float*)(ws + 17563648);
  float* S  = (float*)(ws + 84672512);

  transpose_w<<<dim3(16, 8), 256, 0, stream>>>(W, Wt);
  ht_gemm<<<dim3(4, 64), 256, 0, stream>>>(h, Wt, HT);
  build_yt<<<dim3(128), 256, 0, stream>>>(HT, a, Yt);
  adj_gemm<<<dim3(64, 4), 512, 0, stream>>>(adj, Yt, C, S);
  finalize_gat<<<dim3(4096), 256, 0, stream>>>(C, S, out);
}